// Round 7
// baseline (2836.377 us; speedup 1.0000x reference)
//
#include <hip/hip_runtime.h>

#define B_SZ 128
#define T_SZ 512
#define D_SZ 128
#define H_SZ 512

#define NG 8    // batch groups
#define GB 16   // batch rows per group
#define NS 4    // column slices (blocks per group)
#define SN 128  // columns per slice

typedef _Float16 f16;
typedef _Float16 f16x8 __attribute__((ext_vector_type(8)));
typedef _Float16 f16x4 __attribute__((ext_vector_type(4)));
typedef float f32x4 __attribute__((ext_vector_type(4)));
typedef unsigned long long ull;

// ---------------- W_in transpose ----------------
__global__ __launch_bounds__(256) void transpose_k(const float* __restrict__ in,
                                                   float* __restrict__ out,
                                                   int R, int C) {
  __shared__ float tile[32][33];
  int c0 = blockIdx.x * 32, r0 = blockIdx.y * 32;
  int tx = threadIdx.x & 31, ty = threadIdx.x >> 5;
  for (int i = ty; i < 32; i += 8)
    tile[i][tx] = in[(size_t)(r0 + i) * C + (c0 + tx)];
  __syncthreads();
  for (int i = ty; i < 32; i += 8)
    out[(size_t)(c0 + i) * R + (r0 + tx)] = tile[tx][i];
}

// ---------------- x_in = x @ W_in^T + b ----------------
__global__ __launch_bounds__(256) void input_proj_k(
    const float* __restrict__ x,     // [BT][128]
    const float* __restrict__ WTin,  // [128][512]
    const float* __restrict__ bias,  // [512]
    float* __restrict__ out)         // [BT][512]
{
  __shared__ float xs[32 * 128];
  const int tid = threadIdx.x;
  const size_t r0 = (size_t)blockIdx.x * 32;

  const float4* xg = (const float4*)(x + r0 * D_SZ);
  float4* xs4s = (float4*)xs;
#pragma unroll
  for (int i = 0; i < 4; ++i) xs4s[tid + i * 256] = xg[tid + i * 256];
  __syncthreads();

  const int q = tid & 127;
  const int rg = tid >> 7;
  const float4* W4 = (const float4*)WTin;
  const float4* xs4 = (const float4*)xs;

  float acc[16][4];
#pragma unroll
  for (int r = 0; r < 16; ++r)
#pragma unroll
    for (int c = 0; c < 4; ++c) acc[r][c] = 0.f;

  for (int k4 = 0; k4 < 32; ++k4) {
    float w[4][4];
#pragma unroll
    for (int kk = 0; kk < 4; ++kk) {
      float4 wv = W4[(size_t)(k4 * 4 + kk) * 128 + q];
      w[kk][0] = wv.x; w[kk][1] = wv.y; w[kk][2] = wv.z; w[kk][3] = wv.w;
    }
#pragma unroll
    for (int r = 0; r < 16; ++r) {
      float4 xv = xs4[(rg * 16 + r) * 32 + k4];
      float xk[4] = {xv.x, xv.y, xv.z, xv.w};
#pragma unroll
      for (int kk = 0; kk < 4; ++kk)
#pragma unroll
        for (int c = 0; c < 4; ++c)
          acc[r][c] = fmaf(xk[kk], w[kk][c], acc[r][c]);
    }
  }

  float4 bv = ((const float4*)bias)[q];
  float bb[4] = {bv.x, bv.y, bv.z, bv.w};
#pragma unroll
  for (int r = 0; r < 16; ++r) {
    float4 o;
    o.x = acc[r][0] + bb[0];
    o.y = acc[r][1] + bb[1];
    o.z = acc[r][2] + bb[2];
    o.w = acc[r][3] + bb[3];
    ((float4*)(out + (r0 + rg * 16 + r) * H_SZ))[q] = o;
  }
}

__device__ __forceinline__ float fast_tanh(float y) {
  float e = __expf(2.0f * y);
  return 1.0f - __fdividef(2.0f, e + 1.0f);
}

__device__ __forceinline__ ull ld_agent(const ull* p) {
  return __hip_atomic_load(p, __ATOMIC_RELAXED, __HIP_MEMORY_SCOPE_AGENT);
}

// ---------------- recurrence ----------------
// 32 blocks x 512 threads (8 waves). Exchange via SELF-TAGGED 8B payloads
// (LSB of f16[0] = generation parity) on a depth-2 LLC ring (relaxed sc1).
// Pipeline per iter: issue gathers -> own-K MFMA (no peer dep, covers the
// LLC RTT) -> poll tags -> peer cols into hs[cur] -> barrier -> peer-K MFMA
// -> epilogue -> tagged publish -> own cols into hs[nxt] -> barrier.
// Publish at iter p: slot p&1, tag (p>>1)&1 (holds h_{p+1}); consumer at
// iter s polls slot (s-1)&1, tag ((s-1)>>1)&1. Per-slot tag alternates
// 0,1,0,.. per reuse; memset 0xFF (LSB=1) can't match the first (tag-0)
// polls. ABA-safe: pub(p+2) is after B1(p+2) which is after all lanes
// consumed peers' p+1, which peers published only after consuming p.
__global__ __launch_bounds__(512) void ltc_rec_mfma(
    float* __restrict__ seq,        // [B][T][H]  in: x_in, out: h_seq
    float* __restrict__ h_last,     // [B][H]
    const float* __restrict__ hin,  // [B][H]
    const float* __restrict__ tau,  // [B]
    const float* __restrict__ Wrec, // [H][H] row-major
    f16* __restrict__ ex)           // [2][NG][NS][GB][SN] exchange ring
{
  __shared__ f16 hs[2][GB * H_SZ];  // double-buffered, XOR-swizzled, 2x16KB

  const int tid = threadIdx.x;
  const int g = blockIdx.x & 7;
  const int slice = blockIdx.x >> 3;
  const int w = tid >> 6;          // wave 0..7
  const int l = tid & 63;
  const int m = l & 15;            // batch-in-group (MFMA col)
  const int kg = l >> 4;           // 0..3
  const int jt = slice * SN + w * 16;
  const int j0 = jt + kg * 4;
  const int b = g * GB + m;

  // one-time: A-fragments = W_rec rows (f16)
  f16x8 afrag[16];
  {
    const float* wr = Wrec + (size_t)(jt + m) * H_SZ;
#pragma unroll
    for (int f = 0; f < 16; ++f) {
      const int k0 = f * 32 + kg * 8;
      float4 u0 = *(const float4*)(wr + k0);
      float4 u1 = *(const float4*)(wr + k0 + 4);
      f16x8 a;
      a[0] = (f16)u0.x; a[1] = (f16)u0.y; a[2] = (f16)u0.z; a[3] = (f16)u0.w;
      a[4] = (f16)u1.x; a[5] = (f16)u1.y; a[6] = (f16)u1.z; a[7] = (f16)u1.w;
      afrag[f] = a;
    }
  }

  float hreg[4];
  {
    float4 h0 = *(const float4*)(hin + (size_t)b * H_SZ + j0);
    hreg[0] = h0.x; hreg[1] = h0.y; hreg[2] = h0.z; hreg[3] = h0.w;
  }
  const float itau = 1.0f / tau[b];

  // init: full h_0 into hs[0] as f16
  {
    const int mr = tid >> 5;         // 0..15
    const int c4 = (tid & 31) * 4;
#pragma unroll
    for (int p = 0; p < 4; ++p) {
      const int col = p * SN + c4;
      float4 v = *(const float4*)(hin + (size_t)(g * GB + mr) * H_SZ + col);
      const int e = (mr * H_SZ + col) ^ ((mr & 7) << 3);
      f16x4 hf;
      hf[0] = (f16)v.x; hf[1] = (f16)v.y; hf[2] = (f16)v.z; hf[3] = (f16)v.w;
      *(f16x4*)&hs[0][e] = hf;
    }
  }
  __syncthreads();

  // exchange addressing (ull units)
  const size_t EXB = (size_t)GB * SN;                 // 2048 f16
  const size_t RING_ULL = (size_t)NG * NS * EXB / 4;  // 16384 ull per slot
  ull* pub0 = (ull*)(ex + ((size_t)g * NS + slice) * EXB + (size_t)m * SN + (w * 16 + kg * 4));

  const int gmr = tid >> 5;
  const int gc4 = (tid & 31) * 4;
  const int psa = (slice + 1) & 3, psb = (slice + 2) & 3, psc = (slice + 3) & 3;
  const ull* ga0 = (const ull*)(ex + ((size_t)g * NS + psa) * EXB + (size_t)gmr * SN + gc4);
  const ull* gb0 = (const ull*)(ex + ((size_t)g * NS + psb) * EXB + (size_t)gmr * SN + gc4);
  const ull* gc0 = (const ull*)(ex + ((size_t)g * NS + psc) * EXB + (size_t)gmr * SN + gc4);
  const int ea = (gmr * H_SZ + psa * SN + gc4) ^ ((gmr & 7) << 3);
  const int eb = (gmr * H_SZ + psb * SN + gc4) ^ ((gmr & 7) << 3);
  const int ec = (gmr * H_SZ + psc * SN + gc4) ^ ((gmr & 7) << 3);
  const int eown = (m * H_SZ + j0) ^ ((m & 7) << 3);

  float* seqp = seq + (size_t)b * T_SZ * H_SZ + j0;
  float4 xin = *(const float4*)seqp;  // step-0 x_in prefetch

  for (int s = 0; s < T_SZ; ++s) {
    const int cur = s & 1, nxt = cur ^ 1;

    // ---- issue gather loads for h_s peer slices (pub'd end of iter s-1) ----
    ull w0 = 0, w1 = 0, w2 = 0;
    const size_t proff = nxt ? RING_ULL : 0;          // slot (s-1)&1
    const ull ptag = (ull)(((s - 1) >> 1) & 1);
    if (s > 0) {
      w0 = ld_agent(ga0 + proff);
      w1 = ld_agent(gb0 + proff);
      w2 = ld_agent(gc0 + proff);
    }

    // ---- own-K MFMA (4 frags, k in own slice): covers the gather RTT ----
    f32x4 accA = {0.f, 0.f, 0.f, 0.f};
#pragma unroll
    for (int ff = 0; ff < 4; ++ff) {
      const int f = slice * 4 + ff;
      const int e = (m * H_SZ + f * 32 + kg * 8) ^ ((m & 7) << 3);
      accA = __builtin_amdgcn_mfma_f32_16x16x32_f16(afrag[f], *(const f16x8*)&hs[cur][e], accA, 0, 0, 0);
    }

    if (s > 0) {
      // ---- poll tags; reload only stale words ----
      while ((w0 & 1ULL) != ptag) w0 = ld_agent(ga0 + proff);
      while ((w1 & 1ULL) != ptag) w1 = ld_agent(gb0 + proff);
      while ((w2 & 1ULL) != ptag) w2 = ld_agent(gc0 + proff);
      // ---- peer slices of h_s into hs[cur] peer cols ----
      *(f16x4*)&hs[cur][ea] = __builtin_bit_cast(f16x4, w0);
      *(f16x4*)&hs[cur][eb] = __builtin_bit_cast(f16x4, w1);
      *(f16x4*)&hs[cur][ec] = __builtin_bit_cast(f16x4, w2);
      __syncthreads();  // B1: peer cols visible block-wide
    }

    // ---- peer-K MFMA (12 frags, 2 chains) ----
    f32x4 accB = {0.f, 0.f, 0.f, 0.f};
    f32x4 accC = {0.f, 0.f, 0.f, 0.f};
#pragma unroll
    for (int ff = 0; ff < 6; ++ff) {
      const int f = (slice * 4 + 4 + ff) & 15;
      const int e = (m * H_SZ + f * 32 + kg * 8) ^ ((m & 7) << 3);
      accB = __builtin_amdgcn_mfma_f32_16x16x32_f16(afrag[f], *(const f16x8*)&hs[cur][e], accB, 0, 0, 0);
    }
#pragma unroll
    for (int ff = 6; ff < 12; ++ff) {
      const int f = (slice * 4 + 4 + ff) & 15;
      const int e = (m * H_SZ + f * 32 + kg * 8) ^ ((m & 7) << 3);
      accC = __builtin_amdgcn_mfma_f32_16x16x32_f16(afrag[f], *(const f16x8*)&hs[cur][e], accC, 0, 0, 0);
    }
    f32x4 acc = accA + accB + accC;

    // ---- epilogue ----
    float4 hv;
    hv.x = fmaf(fast_tanh(xin.x + acc[0]) - hreg[0], itau, hreg[0]);
    hv.y = fmaf(fast_tanh(xin.y + acc[1]) - hreg[1], itau, hreg[1]);
    hv.z = fmaf(fast_tanh(xin.z + acc[2]) - hreg[2], itau, hreg[2]);
    hv.w = fmaf(fast_tanh(xin.w + acc[3]) - hreg[3], itau, hreg[3]);
    hreg[0] = hv.x; hreg[1] = hv.y; hreg[2] = hv.z; hreg[3] = hv.w;

    f16x4 hf;
    hf[0] = (f16)hv.x; hf[1] = (f16)hv.y; hf[2] = (f16)hv.z; hf[3] = (f16)hv.w;

    // ---- publish h_{s+1} FIRST: tagged word, slot s&1, tag (s>>1)&1 ----
    {
      ull bits = __builtin_bit_cast(ull, hf);
      bits = (bits & ~1ULL) | (ull)((s >> 1) & 1);
      __hip_atomic_store(pub0 + (cur ? RING_ULL : 0), bits,
                         __ATOMIC_RELAXED, __HIP_MEMORY_SCOPE_AGENT);
    }

    // ---- local tail ----
    *(f16x4*)&hs[nxt][eown] = hf;       // own slice of h_{s+1} (exact f16)
    *(float4*)seqp = hv;                // h_seq output (plain cached)
    seqp += H_SZ;
    xin = *(const float4*)seqp;         // x_in prefetch for s+1

    __syncthreads();  // B2: own cols of hs[nxt] ready for next own-MFMA
  }

  float4 hv;
  hv.x = hreg[0]; hv.y = hreg[1]; hv.z = hreg[2]; hv.w = hreg[3];
  *(float4*)(h_last + (size_t)b * H_SZ + j0) = hv;
}

extern "C" void kernel_launch(void* const* d_in, const int* in_sizes, int n_in,
                              void* d_out, int out_size, void* d_ws, size_t ws_size,
                              hipStream_t stream) {
  const float* x     = (const float*)d_in[0];
  const float* hin   = (const float*)d_in[1];
  const float* tau   = (const float*)d_in[2];
  const float* Win_w = (const float*)d_in[3];
  const float* Win_b = (const float*)d_in[4];
  const float* Wrec  = (const float*)d_in[5];

  float* out    = (float*)d_out;
  float* seq    = out;
  float* h_last = out + (size_t)B_SZ * T_SZ * H_SZ;

  f16*   ex   = (f16*)d_ws;                           // 256 KB (2-slot ring)
  float* WTin = (float*)((char*)d_ws + 262144);       // 256 KB

  // ring to 0xFF: LSB=1 never matches the first (tag-0) poll of each slot.
  hipMemsetAsync(ex, 0xFF, 2 * NG * NS * GB * SN * sizeof(f16), stream);

  dim3 blk(256);
  transpose_k<<<dim3(D_SZ / 32, H_SZ / 32), blk, 0, stream>>>(Win_w, WTin, H_SZ, D_SZ);
  input_proj_k<<<(B_SZ * T_SZ) / 32, blk, 0, stream>>>(x, WTin, Win_b, seq);
  ltc_rec_mfma<<<NG * NS, 512, 0, stream>>>(seq, h_last, hin, tau, Wrec, ex);
}

// Round 8
// 1029.809 us; speedup vs baseline: 2.7543x; 2.7543x over previous
//
#include <hip/hip_runtime.h>

#define B_SZ 128
#define T_SZ 512
#define D_SZ 128
#define H_SZ 512

#define NG 8    // batch groups
#define GB 16   // batch rows per group
#define NS 4    // column slices (blocks per group)
#define SN 128  // columns per slice

typedef _Float16 f16;
typedef _Float16 f16x8 __attribute__((ext_vector_type(8)));
typedef _Float16 f16x4 __attribute__((ext_vector_type(4)));
typedef float f32x4 __attribute__((ext_vector_type(4)));
typedef unsigned long long ull;

// ---------------- W_in transpose ----------------
__global__ __launch_bounds__(256) void transpose_k(const float* __restrict__ in,
                                                   float* __restrict__ out,
                                                   int R, int C) {
  __shared__ float tile[32][33];
  int c0 = blockIdx.x * 32, r0 = blockIdx.y * 32;
  int tx = threadIdx.x & 31, ty = threadIdx.x >> 5;
  for (int i = ty; i < 32; i += 8)
    tile[i][tx] = in[(size_t)(r0 + i) * C + (c0 + tx)];
  __syncthreads();
  for (int i = ty; i < 32; i += 8)
    out[(size_t)(c0 + i) * R + (r0 + tx)] = tile[tx][i];
}

// ---------------- x_in = x @ W_in^T + b ----------------
__global__ __launch_bounds__(256) void input_proj_k(
    const float* __restrict__ x,     // [BT][128]
    const float* __restrict__ WTin,  // [128][512]
    const float* __restrict__ bias,  // [512]
    float* __restrict__ out)         // [BT][512]
{
  __shared__ float xs[32 * 128];
  const int tid = threadIdx.x;
  const size_t r0 = (size_t)blockIdx.x * 32;

  const float4* xg = (const float4*)(x + r0 * D_SZ);
  float4* xs4s = (float4*)xs;
#pragma unroll
  for (int i = 0; i < 4; ++i) xs4s[tid + i * 256] = xg[tid + i * 256];
  __syncthreads();

  const int q = tid & 127;
  const int rg = tid >> 7;
  const float4* W4 = (const float4*)WTin;
  const float4* xs4 = (const float4*)xs;

  float acc[16][4];
#pragma unroll
  for (int r = 0; r < 16; ++r)
#pragma unroll
    for (int c = 0; c < 4; ++c) acc[r][c] = 0.f;

  for (int k4 = 0; k4 < 32; ++k4) {
    float w[4][4];
#pragma unroll
    for (int kk = 0; kk < 4; ++kk) {
      float4 wv = W4[(size_t)(k4 * 4 + kk) * 128 + q];
      w[kk][0] = wv.x; w[kk][1] = wv.y; w[kk][2] = wv.z; w[kk][3] = wv.w;
    }
#pragma unroll
    for (int r = 0; r < 16; ++r) {
      float4 xv = xs4[(rg * 16 + r) * 32 + k4];
      float xk[4] = {xv.x, xv.y, xv.z, xv.w};
#pragma unroll
      for (int kk = 0; kk < 4; ++kk)
#pragma unroll
        for (int c = 0; c < 4; ++c)
          acc[r][c] = fmaf(xk[kk], w[kk][c], acc[r][c]);
    }
  }

  float4 bv = ((const float4*)bias)[q];
  float bb[4] = {bv.x, bv.y, bv.z, bv.w};
#pragma unroll
  for (int r = 0; r < 16; ++r) {
    float4 o;
    o.x = acc[r][0] + bb[0];
    o.y = acc[r][1] + bb[1];
    o.z = acc[r][2] + bb[2];
    o.w = acc[r][3] + bb[3];
    ((float4*)(out + (r0 + rg * 16 + r) * H_SZ))[q] = o;
  }
}

__device__ __forceinline__ float fast_tanh(float y) {
  float e = __expf(2.0f * y);
  return 1.0f - __fdividef(2.0f, e + 1.0f);
}

__device__ __forceinline__ ull ld_agent(const ull* p) {
  return __hip_atomic_load(p, __ATOMIC_RELAXED, __HIP_MEMORY_SCOPE_AGENT);
}

// ---------------- recurrence ----------------
// 32 blocks x 512 threads (8 waves). Exchange via SELF-TAGGED 8B payloads
// (LSB of f16[0] = generation parity) on a depth-2 LLC ring (relaxed sc1).
// Pipeline per iter: issue gathers -> own-K MFMA (no peer dep, covers the
// LLC RTT) -> poll tags -> peer cols into hs[cur] -> B1 -> peer-K MFMA
// -> epilogue -> tagged publish -> own cols into hs[nxt] -> B2.
//
// afrag is stored PRE-ROTATED: afrag[ff] holds W k-block ((slice*4+ff)&15),
// so afrag[0..3] = own-slice K, afrag[4..15] = peer K, and every in-loop
// index is a compile-time literal (rule #20: runtime-indexed ext_vector
// arrays spill to scratch — round 7's 2.4x regression, VGPR 72->48).
__global__ __launch_bounds__(512) void ltc_rec_mfma(
    float* __restrict__ seq,        // [B][T][H]  in: x_in, out: h_seq
    float* __restrict__ h_last,     // [B][H]
    const float* __restrict__ hin,  // [B][H]
    const float* __restrict__ tau,  // [B]
    const float* __restrict__ Wrec, // [H][H] row-major
    f16* __restrict__ ex)           // [2][NG][NS][GB][SN] exchange ring
{
  __shared__ f16 hs[2][GB * H_SZ];  // double-buffered, XOR-swizzled, 2x16KB

  const int tid = threadIdx.x;
  const int g = blockIdx.x & 7;
  const int slice = blockIdx.x >> 3;
  const int w = tid >> 6;          // wave 0..7
  const int l = tid & 63;
  const int m = l & 15;            // batch-in-group (MFMA col)
  const int kg = l >> 4;           // 0..3
  const int jt = slice * SN + w * 16;
  const int j0 = jt + kg * 4;
  const int b = g * GB + m;

  // one-time: A-fragments, pre-rotated so in-loop indices are literals.
  f16x8 afrag[16];
  {
    const float* wr = Wrec + (size_t)(jt + m) * H_SZ;
#pragma unroll
    for (int ff = 0; ff < 16; ++ff) {
      const int f = (slice * 4 + ff) & 15;   // runtime k-block, load-addr only
      const int k0 = f * 32 + kg * 8;
      float4 u0 = *(const float4*)(wr + k0);
      float4 u1 = *(const float4*)(wr + k0 + 4);
      f16x8 a;
      a[0] = (f16)u0.x; a[1] = (f16)u0.y; a[2] = (f16)u0.z; a[3] = (f16)u0.w;
      a[4] = (f16)u1.x; a[5] = (f16)u1.y; a[6] = (f16)u1.z; a[7] = (f16)u1.w;
      afrag[ff] = a;                          // compile-time index
    }
  }

  float hreg[4];
  {
    float4 h0 = *(const float4*)(hin + (size_t)b * H_SZ + j0);
    hreg[0] = h0.x; hreg[1] = h0.y; hreg[2] = h0.z; hreg[3] = h0.w;
  }
  const float itau = 1.0f / tau[b];

  // init: full h_0 into hs[0] as f16
  {
    const int mr = tid >> 5;         // 0..15
    const int c4 = (tid & 31) * 4;
#pragma unroll
    for (int p = 0; p < 4; ++p) {
      const int col = p * SN + c4;
      float4 v = *(const float4*)(hin + (size_t)(g * GB + mr) * H_SZ + col);
      const int e = (mr * H_SZ + col) ^ ((mr & 7) << 3);
      f16x4 hf;
      hf[0] = (f16)v.x; hf[1] = (f16)v.y; hf[2] = (f16)v.z; hf[3] = (f16)v.w;
      *(f16x4*)&hs[0][e] = hf;
    }
  }
  __syncthreads();

  // exchange addressing (ull units)
  const size_t EXB = (size_t)GB * SN;                 // 2048 f16
  const size_t RING_ULL = (size_t)NG * NS * EXB / 4;  // 16384 ull per slot
  ull* pub0 = (ull*)(ex + ((size_t)g * NS + slice) * EXB + (size_t)m * SN + (w * 16 + kg * 4));

  const int gmr = tid >> 5;
  const int gc4 = (tid & 31) * 4;
  const int psa = (slice + 1) & 3, psb = (slice + 2) & 3, psc = (slice + 3) & 3;
  const ull* ga0 = (const ull*)(ex + ((size_t)g * NS + psa) * EXB + (size_t)gmr * SN + gc4);
  const ull* gb0 = (const ull*)(ex + ((size_t)g * NS + psb) * EXB + (size_t)gmr * SN + gc4);
  const ull* gc0 = (const ull*)(ex + ((size_t)g * NS + psc) * EXB + (size_t)gmr * SN + gc4);
  const int ea = (gmr * H_SZ + psa * SN + gc4) ^ ((gmr & 7) << 3);
  const int eb = (gmr * H_SZ + psb * SN + gc4) ^ ((gmr & 7) << 3);
  const int ec = (gmr * H_SZ + psc * SN + gc4) ^ ((gmr & 7) << 3);
  const int eown = (m * H_SZ + j0) ^ ((m & 7) << 3);

  // base byte-offsets for the k-block LDS reads (runtime f folded into
  // address arithmetic; array indices below stay literal)
  int ebase[16];
#pragma unroll
  for (int ff = 0; ff < 16; ++ff) {
    const int f = (slice * 4 + ff) & 15;
    ebase[ff] = (m * H_SZ + f * 32 + kg * 8) ^ ((m & 7) << 3);
  }

  float* seqp = seq + (size_t)b * T_SZ * H_SZ + j0;
  float4 xin = *(const float4*)seqp;  // step-0 x_in prefetch

  for (int s = 0; s < T_SZ; ++s) {
    const int cur = s & 1, nxt = cur ^ 1;

    // ---- issue gather loads for h_s peer slices (pub'd end of iter s-1) ----
    ull w0 = 0, w1 = 0, w2 = 0;
    const size_t proff = nxt ? RING_ULL : 0;          // slot (s-1)&1
    const ull ptag = (ull)(((s - 1) >> 1) & 1);
    if (s > 0) {
      w0 = ld_agent(ga0 + proff);
      w1 = ld_agent(gb0 + proff);
      w2 = ld_agent(gc0 + proff);
    }

    // ---- own-K MFMA (afrag[0..3], no peer dep): covers the gather RTT ----
    f32x4 accA = {0.f, 0.f, 0.f, 0.f};
    accA = __builtin_amdgcn_mfma_f32_16x16x32_f16(afrag[0], *(const f16x8*)&hs[cur][ebase[0]], accA, 0, 0, 0);
    accA = __builtin_amdgcn_mfma_f32_16x16x32_f16(afrag[1], *(const f16x8*)&hs[cur][ebase[1]], accA, 0, 0, 0);
    accA = __builtin_amdgcn_mfma_f32_16x16x32_f16(afrag[2], *(const f16x8*)&hs[cur][ebase[2]], accA, 0, 0, 0);
    accA = __builtin_amdgcn_mfma_f32_16x16x32_f16(afrag[3], *(const f16x8*)&hs[cur][ebase[3]], accA, 0, 0, 0);

    if (s > 0) {
      // ---- poll tags; reload only stale words ----
      while ((w0 & 1ULL) != ptag) w0 = ld_agent(ga0 + proff);
      while ((w1 & 1ULL) != ptag) w1 = ld_agent(gb0 + proff);
      while ((w2 & 1ULL) != ptag) w2 = ld_agent(gc0 + proff);
      // ---- peer slices of h_s into hs[cur] peer cols ----
      *(f16x4*)&hs[cur][ea] = __builtin_bit_cast(f16x4, w0);
      *(f16x4*)&hs[cur][eb] = __builtin_bit_cast(f16x4, w1);
      *(f16x4*)&hs[cur][ec] = __builtin_bit_cast(f16x4, w2);
      __syncthreads();  // B1: peer cols visible block-wide
    }

    // ---- peer-K MFMA (afrag[4..15], 2 chains) ----
    f32x4 accB = {0.f, 0.f, 0.f, 0.f};
    f32x4 accC = {0.f, 0.f, 0.f, 0.f};
    accB = __builtin_amdgcn_mfma_f32_16x16x32_f16(afrag[4],  *(const f16x8*)&hs[cur][ebase[4]],  accB, 0, 0, 0);
    accB = __builtin_amdgcn_mfma_f32_16x16x32_f16(afrag[5],  *(const f16x8*)&hs[cur][ebase[5]],  accB, 0, 0, 0);
    accB = __builtin_amdgcn_mfma_f32_16x16x32_f16(afrag[6],  *(const f16x8*)&hs[cur][ebase[6]],  accB, 0, 0, 0);
    accB = __builtin_amdgcn_mfma_f32_16x16x32_f16(afrag[7],  *(const f16x8*)&hs[cur][ebase[7]],  accB, 0, 0, 0);
    accB = __builtin_amdgcn_mfma_f32_16x16x32_f16(afrag[8],  *(const f16x8*)&hs[cur][ebase[8]],  accB, 0, 0, 0);
    accB = __builtin_amdgcn_mfma_f32_16x16x32_f16(afrag[9],  *(const f16x8*)&hs[cur][ebase[9]],  accB, 0, 0, 0);
    accC = __builtin_amdgcn_mfma_f32_16x16x32_f16(afrag[10], *(const f16x8*)&hs[cur][ebase[10]], accC, 0, 0, 0);
    accC = __builtin_amdgcn_mfma_f32_16x16x32_f16(afrag[11], *(const f16x8*)&hs[cur][ebase[11]], accC, 0, 0, 0);
    accC = __builtin_amdgcn_mfma_f32_16x16x32_f16(afrag[12], *(const f16x8*)&hs[cur][ebase[12]], accC, 0, 0, 0);
    accC = __builtin_amdgcn_mfma_f32_16x16x32_f16(afrag[13], *(const f16x8*)&hs[cur][ebase[13]], accC, 0, 0, 0);
    accC = __builtin_amdgcn_mfma_f32_16x16x32_f16(afrag[14], *(const f16x8*)&hs[cur][ebase[14]], accC, 0, 0, 0);
    accC = __builtin_amdgcn_mfma_f32_16x16x32_f16(afrag[15], *(const f16x8*)&hs[cur][ebase[15]], accC, 0, 0, 0);
    f32x4 acc = accA + accB + accC;

    // ---- epilogue ----
    float4 hv;
    hv.x = fmaf(fast_tanh(xin.x + acc[0]) - hreg[0], itau, hreg[0]);
    hv.y = fmaf(fast_tanh(xin.y + acc[1]) - hreg[1], itau, hreg[1]);
    hv.z = fmaf(fast_tanh(xin.z + acc[2]) - hreg[2], itau, hreg[2]);
    hv.w = fmaf(fast_tanh(xin.w + acc[3]) - hreg[3], itau, hreg[3]);
    hreg[0] = hv.x; hreg[1] = hv.y; hreg[2] = hv.z; hreg[3] = hv.w;

    f16x4 hf;
    hf[0] = (f16)hv.x; hf[1] = (f16)hv.y; hf[2] = (f16)hv.z; hf[3] = (f16)hv.w;

    // ---- publish h_{s+1} FIRST: tagged word, slot s&1, tag (s>>1)&1 ----
    {
      ull bits = __builtin_bit_cast(ull, hf);
      bits = (bits & ~1ULL) | (ull)((s >> 1) & 1);
      __hip_atomic_store(pub0 + (cur ? RING_ULL : 0), bits,
                         __ATOMIC_RELAXED, __HIP_MEMORY_SCOPE_AGENT);
    }

    // ---- local tail ----
    *(f16x4*)&hs[nxt][eown] = hf;       // own slice of h_{s+1} (exact f16)
    *(float4*)seqp = hv;                // h_seq output (plain cached)
    seqp += H_SZ;
    xin = *(const float4*)seqp;         // x_in prefetch for s+1

    __syncthreads();  // B2: own cols of hs[nxt] ready for next own-MFMA
  }

  float4 hv;
  hv.x = hreg[0]; hv.y = hreg[1]; hv.z = hreg[2]; hv.w = hreg[3];
  *(float4*)(h_last + (size_t)b * H_SZ + j0) = hv;
}

extern "C" void kernel_launch(void* const* d_in, const int* in_sizes, int n_in,
                              void* d_out, int out_size, void* d_ws, size_t ws_size,
                              hipStream_t stream) {
  const float* x     = (const float*)d_in[0];
  const float* hin   = (const float*)d_in[1];
  const float* tau   = (const float*)d_in[2];
  const float* Win_w = (const float*)d_in[3];
  const float* Win_b = (const float*)d_in[4];
  const float* Wrec  = (const float*)d_in[5];

  float* out    = (float*)d_out;
  float* seq    = out;
  float* h_last = out + (size_t)B_SZ * T_SZ * H_SZ;

  f16*   ex   = (f16*)d_ws;                           // 256 KB (2-slot ring)
  float* WTin = (float*)((char*)d_ws + 262144);       // 256 KB

  // ring to 0xFF: LSB=1 never matches the first (tag-0) poll of each slot.
  hipMemsetAsync(ex, 0xFF, 2 * NG * NS * GB * SN * sizeof(f16), stream);

  dim3 blk(256);
  transpose_k<<<dim3(D_SZ / 32, H_SZ / 32), blk, 0, stream>>>(Win_w, WTin, H_SZ, D_SZ);
  input_proj_k<<<(B_SZ * T_SZ) / 32, blk, 0, stream>>>(x, WTin, Win_b, seq);
  ltc_rec_mfma<<<NG * NS, 512, 0, stream>>>(seq, h_last, hin, tau, Wrec, ex);
}